// Round 13
// baseline (144.495 us; speedup 1.0000x reference)
//
#include <hip/hip_runtime.h>
#include <hip/hip_bf16.h>

#define BATCH 4
#define S_LEN 2048
#define D_MOD 256
#define NH 8
#define HDIM 32
#define QLOG2E 0.09016844f   // (1/16) * log2(e); folded into Q at projection

typedef short bf16x8 __attribute__((ext_vector_type(8)));
typedef short short4v __attribute__((ext_vector_type(4)));
typedef float f32x4 __attribute__((ext_vector_type(4)));

__device__ __forceinline__ short f2bf(float f) {
    __hip_bfloat16 h = __float2bfloat16(f);
    return *reinterpret_cast<short*>(&h);
}

// ---------------------------------------------------------------------------
// K0: W fp32 [k][n] -> WT bf16 [n][k] for Wq,Wk,Wv,Wo.  grid (4, 32).
// ---------------------------------------------------------------------------
__global__ __launch_bounds__(256) void wtrans_kernel(
    const float* __restrict__ Wq, const float* __restrict__ Wk,
    const float* __restrict__ Wv, const float* __restrict__ Wo,
    short* __restrict__ WT)
{
    const int wsel = blockIdx.x;
    const int k0 = blockIdx.y * 8;
    const float* W = wsel == 0 ? Wq : (wsel == 1 ? Wk : (wsel == 2 ? Wv : Wo));
    short* T = WT + (size_t)wsel * 256 * 256;
    int n = threadIdx.x;
    bf16x8 o;
    #pragma unroll
    for (int kk = 0; kk < 8; ++kk)
        o[kk] = f2bf(W[(size_t)(k0 + kk) * 256 + n]);
    *(bf16x8*)&T[(size_t)n * 256 + k0] = o;
}

// ---------------------------------------------------------------------------
// K1: QKV projection, 16-row blocks, NO LDS (A fragments loaded fp32 direct,
// converted once, reused for all 4 col-tiles).  Q pre-scaled by QLOG2E.
// Q,K packed [bh][s][32]; V transposed [bh][hd][s].  grid (512, 3).
// ---------------------------------------------------------------------------
__global__ __launch_bounds__(256) void qkv_proj_kernel(
    const float* __restrict__ q_in, const float* __restrict__ k_in,
    const float* __restrict__ v_in, const short* __restrict__ WT,
    const float* __restrict__ bq, const float* __restrict__ bk,
    const float* __restrict__ bv,
    short* __restrict__ Qp, short* __restrict__ Kp, short* __restrict__ Vt)
{
    const int mt = blockIdx.x;           // 0..511
    const int seg = blockIdx.y;
    const float* A = seg == 0 ? q_in : (seg == 1 ? k_in : v_in);
    const short* WTs = WT + (size_t)seg * 65536;
    const float* bias = seg == 0 ? bq : (seg == 1 ? bk : bv);
    const int m0 = mt * 16;
    const int tid = threadIdx.x;
    const int w = tid >> 6, l = tid & 63, g = l >> 4, r15 = l & 15;

    // A fragment: row m0+r15, k = kk*32 + 8g .. +8  (fp32 -> bf16, once)
    bf16x8 af[8];
    {
        const float* Ar = A + (size_t)(m0 + r15) * D_MOD + 8 * g;
        #pragma unroll
        for (int kk = 0; kk < 8; ++kk) {
            float4 v0 = *(const float4*)(Ar + kk * 32);
            float4 v1 = *(const float4*)(Ar + kk * 32 + 4);
            af[kk][0] = f2bf(v0.x); af[kk][1] = f2bf(v0.y);
            af[kk][2] = f2bf(v0.z); af[kk][3] = f2bf(v0.w);
            af[kk][4] = f2bf(v1.x); af[kk][5] = f2bf(v1.y);
            af[kk][6] = f2bf(v1.z); af[kk][7] = f2bf(v1.w);
        }
    }

    const int bidx = m0 >> 11;
    const int s_base = m0 & (S_LEN - 1);

    #pragma unroll
    for (int ntl = 0; ntl < 4; ++ntl) {
        int col = w * 64 + ntl * 16 + r15;
        f32x4 acc = {};
        #pragma unroll
        for (int kk = 0; kk < 8; ++kk) {
            bf16x8 b = *(const bf16x8*)&WTs[(size_t)col * 256 + kk * 32 + 8 * g];
            acc = __builtin_amdgcn_mfma_f32_16x16x32_bf16(af[kk], b, acc, 0, 0, 0);
        }
        float bval = bias[col];
        int h = col >> 5, hd = col & 31;
        if (seg == 0) {
            short* Outh = Qp + ((size_t)(bidx * NH + h) * S_LEN) * HDIM;
            #pragma unroll
            for (int r = 0; r < 4; ++r) {
                int s0 = s_base + 4 * g + r;
                Outh[(size_t)s0 * HDIM + hd] = f2bf((acc[r] + bval) * QLOG2E);
            }
        } else if (seg == 1) {
            short* Outh = Kp + ((size_t)(bidx * NH + h) * S_LEN) * HDIM;
            #pragma unroll
            for (int r = 0; r < 4; ++r) {
                int s0 = s_base + 4 * g + r;
                Outh[(size_t)s0 * HDIM + hd] = f2bf(acc[r] + bval);
            }
        } else {
            short* Vh = Vt + ((size_t)(bidx * NH + h) * HDIM + hd) * S_LEN;
            short4v o;
            #pragma unroll
            for (int r = 0; r < 4; ++r) o[r] = f2bf(acc[r] + bval);
            *(short4v*)&Vh[s_base + 4 * g] = o;
        }
    }
}

// ---------------------------------------------------------------------------
// K2: causal attention.  Register-only P (swapped QK^T + permuted-k PV,
// verified R10) + 16-ROW paired q-tiles {u, 127-u}: every block exactly 33
// k-tiles; grid 2048 = 8 blocks/CU x 4 waves -> ~32 waves/CU resident.
// Per-wave state halved (1 Q frag, 2 accs, 1 rowsum).  LDS 9.5 KB.
// ---------------------------------------------------------------------------
__global__ __launch_bounds__(256) void attn_kernel(
    const short* __restrict__ Qp, const short* __restrict__ Kp,
    const short* __restrict__ Vt, short* __restrict__ Ab)
{
    __shared__ float comb[4][16][36];
    __shared__ float psl[4][16];

    const int idx = blockIdx.x;
    const int bh = 4 * (idx & 7) + ((idx >> 3) & 3);   // XCD-local bh groups
    const int u  = idx >> 5;                           // 0..63
    const int b = bh >> 3, hh = bh & 7;
    const int tid = threadIdx.x;
    const int w = tid >> 6, l = tid & 63, g = l >> 4, r15 = l & 15;

    const short* Qph = Qp + (size_t)bh * S_LEN * HDIM;
    const short* Kph = Kp + (size_t)bh * S_LEN * HDIM;
    const short* Vtp = Vt + (size_t)bh * HDIM * S_LEN;
    const f32x4 zero = {};

    #pragma unroll 1
    for (int ph = 0; ph < 2; ++ph) {
        const int q0 = (ph == 0 ? (127 - u) : u) * 16;
        const int ntiles = (q0 + 79) >> 6;             // ceil((q0+16)/64)

        bf16x8 aq = *(const bf16x8*)&Qph[(q0 + r15) * HDIM + 8 * g];

        f32x4 o00 = {}, o01 = {};
        float ps0 = 0.f;

        const short* kp  = Kph + w * 2048 + r15 * 32 + 8 * g;
        const short* vp0 = Vtp + r15 * S_LEN + w * 64 + 4 * g;
        const short* vp1 = vp0 + 16 * S_LEN;

        for (int kt = w; kt < ntiles; kt += 4, kp += 8192, vp0 += 256, vp1 += 256) {
            const int k0 = kt * 64;
            const bool full = (k0 + 63) <= q0;

            // V loads early: hd = r15 / 16+r15, s = k0 + 32ks + {0,16} + 4g..+3
            short4v v000 = *(const short4v*)(vp0);
            short4v v001 = *(const short4v*)(vp0 + 16);
            short4v v010 = *(const short4v*)(vp1);
            short4v v011 = *(const short4v*)(vp1 + 16);
            short4v v100 = *(const short4v*)(vp0 + 32);
            short4v v101 = *(const short4v*)(vp0 + 48);
            short4v v110 = *(const short4v*)(vp1 + 32);
            short4v v111 = *(const short4v*)(vp1 + 48);

            // Swapped QK^T: lane gets S[q=r15][key=k0+16n+4g+r]
            short4v pb[4];
            #pragma unroll
            for (int n = 0; n < 4; ++n) {
                bf16x8 ak = *(const bf16x8*)(kp + n * 512);
                __builtin_amdgcn_s_setprio(1);
                f32x4 s0 = __builtin_amdgcn_mfma_f32_16x16x32_bf16(ak, aq, zero, 0, 0, 0);
                __builtin_amdgcn_s_setprio(0);
                if (full) {
                    #pragma unroll
                    for (int r = 0; r < 4; ++r) {
                        float e0 = exp2f(s0[r]);
                        ps0 += e0;
                        pb[n][r] = f2bf(e0);
                    }
                } else {
                    const int kb = k0 + n * 16 + 4 * g;
                    #pragma unroll
                    for (int r = 0; r < 4; ++r) {
                        float e0 = (kb + r <= q0 + r15) ? exp2f(s0[r]) : 0.0f;
                        ps0 += e0;
                        pb[n][r] = f2bf(e0);
                    }
                }
            }

            // PV with permuted k: A-frag = own P regs, B-frag = matching V order
            bf16x8 pa0 = __builtin_shufflevector(pb[0], pb[1], 0,1,2,3,4,5,6,7);
            bf16x8 pa1 = __builtin_shufflevector(pb[2], pb[3], 0,1,2,3,4,5,6,7);
            bf16x8 bv00 = __builtin_shufflevector(v000, v001, 0,1,2,3,4,5,6,7);
            bf16x8 bv01 = __builtin_shufflevector(v010, v011, 0,1,2,3,4,5,6,7);
            bf16x8 bv10 = __builtin_shufflevector(v100, v101, 0,1,2,3,4,5,6,7);
            bf16x8 bv11 = __builtin_shufflevector(v110, v111, 0,1,2,3,4,5,6,7);

            __builtin_amdgcn_s_setprio(1);
            o00 = __builtin_amdgcn_mfma_f32_16x16x32_bf16(pa0, bv00, o00, 0, 0, 0);
            o01 = __builtin_amdgcn_mfma_f32_16x16x32_bf16(pa0, bv01, o01, 0, 0, 0);
            o00 = __builtin_amdgcn_mfma_f32_16x16x32_bf16(pa1, bv10, o00, 0, 0, 0);
            o01 = __builtin_amdgcn_mfma_f32_16x16x32_bf16(pa1, bv11, o01, 0, 0, 0);
            __builtin_amdgcn_s_setprio(0);
        }

        // rowsum: reduce across the 4 groups (lane ^16, ^32)
        ps0 += __shfl_xor(ps0, 16); ps0 += __shfl_xor(ps0, 32);

        // combine across the 4 key-split waves via LDS
        if (l < 16) psl[w][l] = ps0;
        #pragma unroll
        for (int r = 0; r < 4; ++r) {
            comb[w][4 * g + r][r15]      = o00[r];
            comb[w][4 * g + r][16 + r15] = o01[r];
        }
        __syncthreads();

        // epilogue: 256 threads cover 16 q-rows x 32 hd (2 each)
        {
            int q = tid >> 4, hd0 = (tid & 15) * 2;
            float ps = psl[0][q] + psl[1][q] + psl[2][q] + psl[3][q];
            float inv = __fdividef(1.0f, ps);
            float v0 = comb[0][q][hd0] + comb[1][q][hd0]
                     + comb[2][q][hd0] + comb[3][q][hd0];
            float v1 = comb[0][q][hd0 + 1] + comb[1][q][hd0 + 1]
                     + comb[2][q][hd0 + 1] + comb[3][q][hd0 + 1];
            unsigned uo = (unsigned)(unsigned short)f2bf(v0 * inv)
                        | ((unsigned)(unsigned short)f2bf(v1 * inv) << 16);
            *(unsigned*)&Ab[((size_t)b * S_LEN + q0 + q) * D_MOD + hh * HDIM + hd0] = uo;
        }
        if (ph == 0) __syncthreads();   // comb reuse safe for next phase
    }
}

// ---------------------------------------------------------------------------
// K3: output projection, 16-row blocks, streaming (no LDS).  grid 512.
// ---------------------------------------------------------------------------
__global__ __launch_bounds__(256) void out_proj_kernel(
    const short* __restrict__ Ab, const short* __restrict__ WTo,
    const float* __restrict__ bo, float* __restrict__ out)
{
    const int m0 = blockIdx.x * 16;
    const int tid = threadIdx.x;
    const int w = tid >> 6, l = tid & 63, g = l >> 4, r15 = l & 15;

    bf16x8 af[8];
    #pragma unroll
    for (int kk = 0; kk < 8; ++kk)
        af[kk] = *(const bf16x8*)&Ab[(size_t)(m0 + r15) * D_MOD + kk * 32 + 8 * g];

    #pragma unroll
    for (int ntl = 0; ntl < 4; ++ntl) {
        int col = w * 64 + ntl * 16 + r15;
        f32x4 acc = {};
        #pragma unroll
        for (int kk = 0; kk < 8; ++kk) {
            bf16x8 bfr = *(const bf16x8*)&WTo[(size_t)col * 256 + kk * 32 + 8 * g];
            acc = __builtin_amdgcn_mfma_f32_16x16x32_bf16(af[kk], bfr, acc, 0, 0, 0);
        }
        float bval = bo[col];
        #pragma unroll
        for (int r = 0; r < 4; ++r)
            out[(size_t)(m0 + 4 * g + r) * D_MOD + col] = acc[r] + bval;
    }
}

extern "C" void kernel_launch(void* const* d_in, const int* in_sizes, int n_in,
                              void* d_out, int out_size, void* d_ws, size_t ws_size,
                              hipStream_t stream) {
    const float* q_in = (const float*)d_in[0];
    const float* k_in = (const float*)d_in[1];
    const float* v_in = (const float*)d_in[2];
    // d_in[3] = mask: causal tril, applied analytically.
    const float* Wq = (const float*)d_in[4];
    const float* bq = (const float*)d_in[5];
    const float* Wk = (const float*)d_in[6];
    const float* bk = (const float*)d_in[7];
    const float* Wv = (const float*)d_in[8];
    const float* bv = (const float*)d_in[9];
    const float* Wo = (const float*)d_in[10];
    const float* bo = (const float*)d_in[11];
    float* out = (float*)d_out;

    const size_t NTOK = (size_t)BATCH * S_LEN * D_MOD;  // 2M elements
    short* WT = (short*)d_ws;           // 4 x 256 x 256 bf16 = 512 KB
    short* Qp = WT + 4 * 65536;         // packed [bh][s][32], pre-scaled
    short* Kp = Qp + NTOK;              // packed [bh][s][32]
    short* Vt = Kp + NTOK;              // transposed [bh][hd][s]
    short* Ab = Vt + NTOK;              // [b][s][256]

    wtrans_kernel<<<dim3(4, 32), 256, 0, stream>>>(Wq, Wk, Wv, Wo, WT);
    qkv_proj_kernel<<<dim3(512, 3), 256, 0, stream>>>(
        q_in, k_in, v_in, WT, bq, bk, bv, Qp, Kp, Vt);
    attn_kernel<<<2048, 256, 0, stream>>>(Qp, Kp, Vt, Ab);
    out_proj_kernel<<<512, 256, 0, stream>>>(Ab, WT + 3 * 65536, bo, out);
}